// Round 1
// 667.782 us; speedup vs baseline: 1.0887x; 1.0887x over previous
//
#include <hip/hip_runtime.h>
#include <stdint.h>

typedef __bf16 bf16x8 __attribute__((ext_vector_type(8)));
typedef float f32x4 __attribute__((ext_vector_type(4)));

__device__ __forceinline__ unsigned short f2bf(float f) {
    union { float f; uint32_t i; } v;
    v.f = f;
    uint32_t x = v.i;
    return (unsigned short)((x + 0x7FFFu + ((x >> 16) & 1u)) >> 16);  // RNE
}

// async global->LDS, 16B per lane. LDS dest is wave-uniform base + lane*16;
// the GLOBAL source address is per-lane free (this is what enables swizzling).
typedef __attribute__((address_space(3))) unsigned int lds_u32;
typedef __attribute__((address_space(1))) const unsigned int glob_u32;
__device__ __forceinline__ void gld16(const unsigned short* g, unsigned short* l) {
    __builtin_amdgcn_global_load_lds((glob_u32*)g, (lds_u32*)l, 16, 0, 0);
}

// ---------------------------------------------------------------------------
// All weight prep in ONE launch (range-dispatch on blockIdx.x, 9220 blocks).
// ---------------------------------------------------------------------------
__global__ __launch_bounds__(256) void prep_weights(
    const float* __restrict__ Wq, const float* __restrict__ Wk,
    const float* __restrict__ Wm, const float* __restrict__ W1,
    const float* __restrict__ W2, const float* __restrict__ bq,
    const float* __restrict__ bk,
    unsigned short* __restrict__ wqb, unsigned short* __restrict__ wkb,
    unsigned short* __restrict__ wmb, unsigned short* __restrict__ w1b,
    unsigned short* __restrict__ w2b, float* __restrict__ bqp,
    float* __restrict__ bkp)
{
    const int b = blockIdx.x, t = threadIdx.x;
    if (b < 2048) {
        const float* in = (b < 1024) ? Wq : Wk;
        unsigned short* out = (b < 1024) ? wqb : wkb;
        const int i = ((b & 1023) * 256 + t) * 4;
        const int row = i >> 10, col = i & 1023;
        const float4 v = *(const float4*)(in + ((row & 63) * 16 + (row >> 6)) * 1024 + col);
        out[i + 0] = f2bf(v.x); out[i + 1] = f2bf(v.y);
        out[i + 2] = f2bf(v.z); out[i + 3] = f2bf(v.w);
    } else if (b < 3072) {
        const int i = ((b - 2048) * 256 + t) * 4;
        const int row = i >> 10, c0 = i & 1023;
        const float* r = Wm + (size_t)row * 1024;
#pragma unroll
        for (int j = 0; j < 4; ++j) {
            const int c = c0 + j;
            wmb[i + j] = f2bf(r[(c & 63) * 16 + (c >> 6)]);
        }
    } else if (b < 7168) {
        const int i = ((b - 3072) * 256 + t) * 4;
        const float4 v = *(const float4*)(W1 + i);
        w1b[i + 0] = f2bf(v.x); w1b[i + 1] = f2bf(v.y);
        w1b[i + 2] = f2bf(v.z); w1b[i + 3] = f2bf(v.w);
    } else if (b < 9216) {
        const int i = ((b - 7168) * 256 + t) * 4;
        const float4 v = *(const float4*)(W2 + i);
        w2b[i + 0] = f2bf(v.x); w2b[i + 1] = f2bf(v.y);
        w2b[i + 2] = f2bf(v.z); w2b[i + 3] = f2bf(v.w);
    } else {
        const int o = (b - 9216) * 256 + t;
        const int src = (o & 63) * 16 + (o >> 6);
        bqp[o] = bq[src];
        bkp[o] = bk[src];
    }
}

// ---------------------------------------------------------------------------
// f32 [R][C] -> bf16 [C][R], batched over blockIdx.z (proj).
// ---------------------------------------------------------------------------
__global__ __launch_bounds__(256) void cvt_transpose(
    const float* __restrict__ in, unsigned short* __restrict__ out,
    int R, int C)
{
    __shared__ unsigned short tile[32][33];
    const size_t bo = (size_t)blockIdx.z * R * C;
    const int c0 = blockIdx.x * 32, r0 = blockIdx.y * 32;
    const int tx = threadIdx.x & 31, ty = threadIdx.x >> 5;
#pragma unroll
    for (int i = 0; i < 4; ++i)
        tile[ty + i * 8][tx] = f2bf(in[bo + (size_t)(r0 + ty + i * 8) * C + (c0 + tx)]);
    __syncthreads();
#pragma unroll
    for (int i = 0; i < 4; ++i)
        out[bo + (size_t)(c0 + ty + i * 8) * R + (r0 + tx)] = tile[tx][ty + i * 8];
}

// Fused x + source transpose: z = tensor*4 + batch.
__global__ __launch_bounds__(256) void cvt_transpose_xs(
    const float* __restrict__ x, const float* __restrict__ s,
    unsigned short* __restrict__ xt, unsigned short* __restrict__ st)
{
    __shared__ unsigned short tile[32][33];
    const int z = blockIdx.z;
    const float* in = (z < 4) ? x : s;
    unsigned short* out = (z < 4) ? xt : st;
    const size_t bo = (size_t)(z & 3) * 1024 * 4096;
    const int c0 = blockIdx.x * 32, r0 = blockIdx.y * 32;
    const int tx = threadIdx.x & 31, ty = threadIdx.x >> 5;
#pragma unroll
    for (int i = 0; i < 4; ++i)
        tile[ty + i * 8][tx] = f2bf(in[bo + (size_t)(r0 + ty + i * 8) * 4096 + (c0 + tx)]);
    __syncthreads();
#pragma unroll
    for (int i = 0; i < 4; ++i)
        out[bo + (size_t)(c0 + ty + i * 8) * 1024 + (r0 + tx)] = tile[tx][ty + i * 8];
}

// ---------------------------------------------------------------------------
// OLD 128x128 2-barrier GEMM. Kept ONLY for the kp projection (N'=128 < 256).
// ---------------------------------------------------------------------------
template<int LDA, int LDB, int LDC, int KD, int SPLIT, bool CONCAT>
__global__ __launch_bounds__(256) void gemm_bt(
    const unsigned short* __restrict__ A,
    const unsigned short* __restrict__ A2, int K1,
    const unsigned short* __restrict__ BT,
    unsigned short* __restrict__ C, float* __restrict__ Cf,
    long long strideA, long long strideB, long long strideC,
    const float* __restrict__ bias_m,
    const float* __restrict__ bias_n,
    const float* __restrict__ bn_g,
    const float* __restrict__ bn_b,
    const float* __restrict__ bn_mu,
    const float* __restrict__ bn_var)
{
    constexpr int KPB = KD / SPLIT;
    __shared__ __align__(16) unsigned short As[128 * 64];
    __shared__ __align__(16) unsigned short Bs[128 * 64];

    const int z = blockIdx.z;
    const int batch = z / SPLIT;
    const int kbase = (z % SPLIT) * KPB;
    const int m0 = blockIdx.y * 128, n0 = blockIdx.x * 128;
    const unsigned short* Ab  = A + (size_t)batch * strideA;
    const unsigned short* A2b = CONCAT ? A2 + (size_t)batch * strideA
                                       : (const unsigned short*)0;
    const unsigned short* Bb = BT + (size_t)batch * strideB;

    const int t = threadIdx.x;
    const int lane = t & 63, wid = t >> 6;
    const int wm = wid >> 1, wn = wid & 1;
    const int r16 = lane & 15, quad = lane >> 4;

    f32x4 acc[4][4];
    const f32x4 zf = {0.f, 0.f, 0.f, 0.f};
#pragma unroll
    for (int i = 0; i < 4; ++i)
#pragma unroll
        for (int j = 0; j < 4; ++j) acc[i][j] = zf;

    for (int kt = kbase; kt < kbase + KPB; kt += 64) {
        const unsigned short* Asrc = Ab;
        int kk = kt;
        if (CONCAT && kt >= K1) { Asrc = A2b; kk = kt - K1; }
#pragma unroll
        for (int i = 0; i < 4; ++i) {
            const int p = i * 256 + t;
            const int row = p >> 3, slot = p & 7;
            const int kc = (slot ^ (row & 7)) * 8;
            gld16(&Asrc[(size_t)(m0 + row) * LDA + kk + kc], &As[p * 8]);
            gld16(&Bb[(size_t)(n0 + row) * LDB + kt + kc], &Bs[p * 8]);
        }
        __syncthreads();
#pragma unroll
        for (int s = 0; s < 2; ++s) {
            bf16x8 af[4], bfb[4];
#pragma unroll
            for (int i = 0; i < 4; ++i) {
                const int ra = wm * 64 + i * 16 + r16;
                const int rb = wn * 64 + i * 16 + r16;
                af[i]  = *(const bf16x8*)&As[(ra * 8 + ((s * 4 + quad) ^ (ra & 7))) * 8];
                bfb[i] = *(const bf16x8*)&Bs[(rb * 8 + ((s * 4 + quad) ^ (rb & 7))) * 8];
            }
#pragma unroll
            for (int mi = 0; mi < 4; ++mi)
#pragma unroll
                for (int ni = 0; ni < 4; ++ni)
                    acc[mi][ni] = __builtin_amdgcn_mfma_f32_16x16x32_bf16(
                        af[mi], bfb[ni], acc[mi][ni], 0, 0, 0);
        }
        __syncthreads();
    }

    unsigned short* Cb = C ? C + (size_t)z * strideC : (unsigned short*)0;
    float* Cfb = Cf ? Cf + (size_t)z * strideC : (float*)0;
    const bool has_bn = (bn_g != 0);
#pragma unroll
    for (int ni = 0; ni < 4; ++ni) {
        const int gn = n0 + wn * 64 + ni * 16 + r16;
        const float addn = bias_n ? bias_n[gn] : 0.f;
        float g = 1.f, bb = 0.f, mu = 0.f, rstd = 1.f;
        if (has_bn) {
            g = bn_g[gn]; bb = bn_b[gn]; mu = bn_mu[gn];
            rstd = rsqrtf(bn_var[gn] + 1e-3f);
        }
#pragma unroll
        for (int mi = 0; mi < 4; ++mi) {
            const int gm0 = m0 + wm * 64 + mi * 16 + quad * 4;
#pragma unroll
            for (int r = 0; r < 4; ++r) {
                float v = acc[mi][ni][r] + addn;
                if (bias_m) v += bias_m[gm0 + r];
                if (has_bn) { v = g * (v - mu) * rstd + bb; v = fmaxf(v, 0.f); }
                const size_t idx = (size_t)(gm0 + r) * LDC + gn;
                if (Cfb) Cfb[idx] = v;
                else     Cb[idx]  = f2bf(v);
            }
        }
    }
}

// ---------------------------------------------------------------------------
// NEW: 256x256 8-phase GEMM (8 waves 2Mx4N, BK=64, dbuf LDS 128 KiB).
// Counted vmcnt(6) once per K-tile; global_load_lds staging with the proven
// XOR chunk swizzle (slot = k16 ^ (row&7), 0 bank conflicts).
//
// Staging conveyor (units of 16 KB = 2 gld/thread), 7-phase lead:
//   U0 = A rows {0-63,128-191}   read @ph1 only    issued @ (X+?).ph2
//   U1 = B rows {0-127}          read @ph1+ph2     issued @ ph3
//   U2 = B rows {128-255}        read @ph1+ph2     issued @ ph4
//   U3 = A rows {64-127,192-255} read @ph3 only    issued @ ph1 (next buf)
// During tile X: ph1 issues U3(X+1) -> nxt buf; ph2/3/4 issue U0/U1/U2(X+2)
// -> cur buf into regions already dead (read completion published by the
// preceding phase barrier). s_waitcnt vmcnt(6) at ph4 confirms everything
// through U3(X+1), i.e. tile X+1 fully staged, with 3 units still in flight.
// ---------------------------------------------------------------------------
#define BAR   __builtin_amdgcn_s_barrier()
#define LGKM0 asm volatile("s_waitcnt lgkmcnt(0)" ::: "memory")
#define PRIO1 __builtin_amdgcn_s_setprio(1)
#define PRIO0 __builtin_amdgcn_s_setprio(0)

#define ST_A(dst, kt, i0, i1) do {                                          \
    const unsigned short* S_ = Ab; long long kk_ = (kt);                    \
    if (CONCAT && (kt) >= K1) { S_ = A2b; kk_ = (kt) - K1; }                \
    gld16(&S_[offA[i0] + kk_], (dst) + po[i0]);                             \
    gld16(&S_[offA[i1] + kk_], (dst) + po[i1]); } while (0)

#define ST_B(dst, kt, i0, i1) do {                                          \
    gld16(&Bb[offB[i0] + (kt)], (dst) + po[i0]);                            \
    gld16(&Bb[offB[i1] + (kt)], (dst) + po[i1]); } while (0)

#define RD_A(mh, AC) do {                                                   \
    _Pragma("unroll") for (int mi = 0; mi < 4; ++mi) {                      \
        const int ra = wm * 128 + (mh) * 64 + mi * 16 + r16;                \
        _Pragma("unroll") for (int ks = 0; ks < 2; ++ks) {                  \
            const int c_ = ks * 4 + quad;                                   \
            a[mi][ks] = *(const bf16x8*)&(AC)[(ra * 8 + (c_ ^ (ra & 7))) * 8]; \
        } } } while (0)

#define RD_B(np, BC) do {                                                   \
    _Pragma("unroll") for (int i = 0; i < 2; ++i) {                         \
        const int rb = wn * 64 + ((np) * 2 + i) * 16 + r16;                 \
        _Pragma("unroll") for (int ks = 0; ks < 2; ++ks) {                  \
            const int c_ = ks * 4 + quad;                                   \
            b[(np) * 2 + i][ks] = *(const bf16x8*)&(BC)[(rb * 8 + (c_ ^ (rb & 7))) * 8]; \
        } } } while (0)

#define MFMA_PH(mh, np) do {                                                \
    _Pragma("unroll") for (int mi = 0; mi < 4; ++mi)                        \
    _Pragma("unroll") for (int i = 0; i < 2; ++i)                           \
    _Pragma("unroll") for (int ks = 0; ks < 2; ++ks)                        \
        acc[(mh) * 4 + mi][(np) * 2 + i] =                                  \
            __builtin_amdgcn_mfma_f32_16x16x32_bf16(                        \
                a[mi][ks], b[(np) * 2 + i][ks],                             \
                acc[(mh) * 4 + mi][(np) * 2 + i], 0, 0, 0); } while (0)

#define TILE_BODY(XV, AC, BC, AN, BN_) do {                                 \
    const int kt1_ = ((XV) + 1) * 64, kt2_ = ((XV) + 2) * 64;               \
    const bool g1_ = ((XV) + 1) < nt, g2_ = ((XV) + 2) < nt;                \
    /* phase 1: A(mh0) 8 + B(n01) 4 reads; stage U3(X+1) -> next buf */     \
    RD_A(0, AC); RD_B(0, BC);                                               \
    if (g1_) ST_A(AN, kt1_, 1, 3);                                          \
    BAR; LGKM0; PRIO1; MFMA_PH(0, 0); PRIO0; BAR;                           \
    /* phase 2: B(n23) 4 reads; stage U0(X+2) -> cur buf (A rows dead) */   \
    RD_B(1, BC);                                                            \
    if (g2_) ST_A(AC, kt2_, 0, 2);                                          \
    BAR; LGKM0; PRIO1; MFMA_PH(0, 1); PRIO0; BAR;                           \
    /* phase 3: A(mh1) 8 reads; stage U1(X+2) -> cur buf (B0-127 dead) */   \
    RD_A(1, AC);                                                            \
    if (g2_) ST_B(BC, kt2_, 0, 1);                                          \
    BAR; LGKM0; PRIO1; MFMA_PH(1, 1); PRIO0; BAR;                           \
    /* phase 4: stage U2(X+2); counted vmcnt -> tile X+1 confirmed */       \
    if (g2_) { ST_B(BC, kt2_, 2, 3);                                        \
               asm volatile("s_waitcnt vmcnt(6)" ::: "memory"); }           \
    else     { asm volatile("s_waitcnt vmcnt(0)" ::: "memory"); }           \
    BAR; LGKM0; PRIO1; MFMA_PH(1, 0); PRIO0; BAR;                           \
} while (0)

template<int LDA, int LDB, int LDC, int KD, bool CONCAT>
__global__ __launch_bounds__(512, 2) void gemm256(
    const unsigned short* __restrict__ A,
    const unsigned short* __restrict__ A2, int K1,
    const unsigned short* __restrict__ BT,
    unsigned short* __restrict__ C, float* __restrict__ Cf,
    long long strideA, long long strideB, long long strideC,
    const float* __restrict__ bias_m,
    const float* __restrict__ bias_n,
    const float* __restrict__ bn_g,
    const float* __restrict__ bn_b,
    const float* __restrict__ bn_mu,
    const float* __restrict__ bn_var)
{
    static_assert(KD % 128 == 0, "nt must be even");
    constexpr int nt = KD / 64;
    constexpr int TILE = 256 * 64;
    __shared__ __align__(16) unsigned short As[2 * TILE];
    __shared__ __align__(16) unsigned short Bs[2 * TILE];
    unsigned short* As0 = As;        unsigned short* As1 = As + TILE;
    unsigned short* Bs0 = Bs;        unsigned short* Bs1 = Bs + TILE;

    const int batch = blockIdx.z;
    // Bijective XCD-contiguous tile remap (all grids here have nwg % 8 == 0).
    const int gx = gridDim.x;
    const int nwg = gx * gridDim.y;
    int flat = blockIdx.y * gx + blockIdx.x;
    flat = (flat & 7) * (nwg >> 3) + (flat >> 3);
    const int n0 = (flat % gx) * 256;
    const int m0 = (flat / gx) * 256;

    const unsigned short* Ab  = A + (size_t)batch * strideA;
    const unsigned short* A2b = CONCAT ? A2 + (size_t)batch * strideA
                                       : (const unsigned short*)0;
    const unsigned short* Bb  = BT + (size_t)batch * strideB;

    const int t = threadIdx.x;
    const int lane = t & 63, wid = t >> 6;
    const int wm = wid >> 2, wn = wid & 3;       // 2 x 4 wave grid
    const int r16 = lane & 15, quad = lane >> 4;

    // Precomputed staging offsets (statically indexed only).
    long long offA[4], offB[4];
    int po[4];
#pragma unroll
    for (int i = 0; i < 4; ++i) {
        const int p = i * 512 + t, row = p >> 3;
        const int kc = ((p & 7) ^ (row & 7)) * 8;
        po[i] = p * 8;
        offA[i] = (long long)(m0 + row) * LDA + kc;
        offB[i] = (long long)(n0 + row) * LDB + kc;
    }

    f32x4 acc[8][4];
    const f32x4 zf = {0.f, 0.f, 0.f, 0.f};
#pragma unroll
    for (int i = 0; i < 8; ++i)
#pragma unroll
        for (int j = 0; j < 4; ++j) acc[i][j] = zf;

    bf16x8 a[4][2], b[4][2];

    // Prologue: U0..U3(T0), U0..U2(T1); vmcnt(6) => T0 fully staged.
    ST_A(As0, 0, 0, 2);
    ST_B(Bs0, 0, 0, 1);
    ST_B(Bs0, 0, 2, 3);
    ST_A(As0, 0, 1, 3);
    ST_A(As1, 64, 0, 2);
    ST_B(Bs1, 64, 0, 1);
    ST_B(Bs1, 64, 2, 3);
    asm volatile("s_waitcnt vmcnt(6)" ::: "memory");
    BAR;

#pragma unroll 1
    for (int X2 = 0; X2 < nt; X2 += 2) {
        TILE_BODY(X2,     As0, Bs0, As1, Bs1);
        TILE_BODY(X2 + 1, As1, Bs1, As0, Bs0);
    }

    unsigned short* Cb = C ? C + (size_t)batch * strideC : (unsigned short*)0;
    float* Cfb = Cf ? Cf + (size_t)batch * strideC : (float*)0;
    const bool has_bn = (bn_g != 0);
#pragma unroll
    for (int ni = 0; ni < 4; ++ni) {
        const int gn = n0 + wn * 64 + ni * 16 + r16;
        const float addn = bias_n ? bias_n[gn] : 0.f;
        float g = 1.f, bb = 0.f, mu = 0.f, rstd = 1.f;
        if (has_bn) {
            g = bn_g[gn]; bb = bn_b[gn]; mu = bn_mu[gn];
            rstd = rsqrtf(bn_var[gn] + 1e-3f);
        }
#pragma unroll
        for (int mi = 0; mi < 8; ++mi) {
            const int gm0 = m0 + wm * 128 + mi * 16 + quad * 4;
#pragma unroll
            for (int r = 0; r < 4; ++r) {
                float v = acc[mi][ni][r] + addn;
                if (bias_m) v += bias_m[gm0 + r];
                if (has_bn) { v = g * (v - mu) * rstd + bb; v = fmaxf(v, 0.f); }
                const size_t idx = (size_t)(gm0 + r) * LDC + gn;
                if (Cfb) Cfb[idx] = v;
                else     Cb[idx]  = f2bf(v);
            }
        }
    }
}

#undef TILE_BODY
#undef MFMA_PH
#undef RD_B
#undef RD_A
#undef ST_B
#undef ST_A
#undef PRIO0
#undef PRIO1
#undef LGKM0
#undef BAR

// kp split-K reduce: kpb[b][j] = bf16( sum_p acc[b*8+p][j] )
__global__ __launch_bounds__(256) void reduce_kp(
    const float* __restrict__ acc, unsigned short* __restrict__ kpb)
{
    const int j = (blockIdx.x * 256 + threadIdx.x) * 4;
    const int b = j >> 17, jj = j & 131071;
    const float* base = acc + (size_t)b * 8 * 131072 + jj;
    float4 s = *(const float4*)base;
#pragma unroll
    for (int p = 1; p < 8; ++p) {
        const float4 v = *(const float4*)(base + (size_t)p * 131072);
        s.x += v.x; s.y += v.y; s.z += v.z; s.w += v.w;
    }
    kpb[j + 0] = f2bf(s.x); kpb[j + 1] = f2bf(s.y);
    kpb[j + 2] = f2bf(s.z); kpb[j + 3] = f2bf(s.w);
}

// ---------------------------------------------------------------------------
// MFMA flash-attention (unchanged; channel order o' = h*64+dh).
// ---------------------------------------------------------------------------
__global__ __launch_bounds__(256) void attn_fused(
    const unsigned short* __restrict__ qT,
    const unsigned short* __restrict__ kp,
    unsigned short* __restrict__ msgT)
{
    constexpr int QS = 72, KS = 72, VS = 136, PS = 136;
    __shared__ __align__(16) unsigned short QKP[128 * QS + 128 * KS];
    __shared__ __align__(16) unsigned short Vs[64 * VS];
    unsigned short* Qs = QKP;
    unsigned short* Ks = QKP + 128 * QS;
    unsigned short* Ps = QKP;

    const int t = threadIdx.x;
    const int lane = t & 63, w = t >> 6;
    const int r16 = lane & 15, quad = lane >> 4;
    const int h = blockIdx.y, n0 = blockIdx.x * 128;
    const size_t b = blockIdx.z;

    const unsigned short* qbase = qT + (b * 4096 + n0) * 1024 + h * 64;
    const unsigned short* kbase = kp + (b * 1024 + h * 64) * 128;

#pragma unroll
    for (int i = 0; i < 4; ++i) {
        const int c = i * 256 + t;
        const int n = c >> 3, dh0 = (c & 7) * 8;
        *(int4*)&Qs[n * QS + dh0] = *(const int4*)&qbase[(size_t)n * 1024 + dh0];
    }
#pragma unroll
    for (int i = 0; i < 4; ++i) {
        const int c = i * 256 + t;
        const int kkq = c & 3, dh = (c >> 2) & 63, kkh = c >> 8;
        const int kk0 = kkh * 32 + kkq * 8;
        const bf16x8 v = *(const bf16x8*)&kbase[(size_t)dh * 128 + kk0];
        *(bf16x8*)&Vs[dh * VS + kk0] = v;
        const unsigned short* vs = (const unsigned short*)&v;
#pragma unroll
        for (int j = 0; j < 8; ++j) Ks[(kk0 + j) * KS + dh] = vs[j];
    }
    __syncthreads();

    f32x4 S[2][8];
    const f32x4 zf = {0.f, 0.f, 0.f, 0.f};
#pragma unroll
    for (int mi = 0; mi < 2; ++mi)
#pragma unroll
        for (int ni = 0; ni < 8; ++ni) S[mi][ni] = zf;

    bf16x8 aq[2][2];
#pragma unroll
    for (int mi = 0; mi < 2; ++mi)
#pragma unroll
        for (int ks = 0; ks < 2; ++ks)
            aq[mi][ks] = *(const bf16x8*)&Qs[(w * 32 + mi * 16 + r16) * QS + ks * 32 + quad * 8];
#pragma unroll
    for (int ni = 0; ni < 8; ++ni) {
        const bf16x8 b0 = *(const bf16x8*)&Ks[(ni * 16 + r16) * KS + quad * 8];
        const bf16x8 b1 = *(const bf16x8*)&Ks[(ni * 16 + r16) * KS + 32 + quad * 8];
#pragma unroll
        for (int mi = 0; mi < 2; ++mi) {
            S[mi][ni] = __builtin_amdgcn_mfma_f32_16x16x32_bf16(aq[mi][0], b0, S[mi][ni], 0, 0, 0);
            S[mi][ni] = __builtin_amdgcn_mfma_f32_16x16x32_bf16(aq[mi][1], b1, S[mi][ni], 0, 0, 0);
        }
    }

    __syncthreads();

    float linv[2][4];
#pragma unroll
    for (int mi = 0; mi < 2; ++mi) {
        float e[8][4];
        float rs0 = 0.f, rs1 = 0.f, rs2 = 0.f, rs3 = 0.f;
#pragma unroll
        for (int ni = 0; ni < 8; ++ni) {
            e[ni][0] = __expf(S[mi][ni][0] * 0.125f); rs0 += e[ni][0];
            e[ni][1] = __expf(S[mi][ni][1] * 0.125f); rs1 += e[ni][1];
            e[ni][2] = __expf(S[mi][ni][2] * 0.125f); rs2 += e[ni][2];
            e[ni][3] = __expf(S[mi][ni][3] * 0.125f); rs3 += e[ni][3];
        }
        float rs[4] = {rs0, rs1, rs2, rs3};
#pragma unroll
        for (int r = 0; r < 4; ++r) {
            float s = rs[r];
            s += __shfl_xor(s, 1); s += __shfl_xor(s, 2);
            s += __shfl_xor(s, 4); s += __shfl_xor(s, 8);
            linv[mi][r] = 1.f / s;
        }
#pragma unroll
        for (int ni = 0; ni < 8; ++ni)
#pragma unroll
            for (int r = 0; r < 4; ++r)
                Ps[(w * 32 + mi * 16 + quad * 4 + r) * PS + ni * 16 + r16] = f2bf(e[ni][r]);
    }
    __syncthreads();

    f32x4 O[2][4];
#pragma unroll
    for (int mi = 0; mi < 2; ++mi)
#pragma unroll
        for (int ni = 0; ni < 4; ++ni) O[mi][ni] = zf;

    bf16x8 ap[2][4];
#pragma unroll
    for (int mi = 0; mi < 2; ++mi)
#pragma unroll
        for (int ks = 0; ks < 4; ++ks)
            ap[mi][ks] = *(const bf16x8*)&Ps[(w * 32 + mi * 16 + r16) * PS + ks * 32 + quad * 8];
#pragma unroll
    for (int ni = 0; ni < 4; ++ni)
#pragma unroll
        for (int ks = 0; ks < 4; ++ks) {
            const bf16x8 bv = *(const bf16x8*)&Vs[(ni * 16 + r16) * VS + ks * 32 + quad * 8];
#pragma unroll
            for (int mi = 0; mi < 2; ++mi)
                O[mi][ni] = __builtin_amdgcn_mfma_f32_16x16x32_bf16(ap[mi][ks], bv, O[mi][ni], 0, 0, 0);
        }

    unsigned short* ob = msgT + (b * 4096 + n0) * 1024 + h * 64;
#pragma unroll
    for (int mi = 0; mi < 2; ++mi)
#pragma unroll
        for (int ni = 0; ni < 4; ++ni)
#pragma unroll
            for (int r = 0; r < 4; ++r)
                ob[(size_t)(w * 32 + mi * 16 + quad * 4 + r) * 1024 + ni * 16 + r16] =
                    f2bf(O[mi][ni][r] * linv[mi][r]);
}

// ---------------------------------------------------------------------------
extern "C" void kernel_launch(void* const* d_in, const int* in_sizes, int n_in,
                              void* d_out, int out_size, void* d_ws, size_t ws_size,
                              hipStream_t stream)
{
    (void)in_sizes; (void)n_in; (void)out_size; (void)ws_size;
    const float* x    = (const float*)d_in[0];
    const float* srcp = (const float*)d_in[1];
    const float* Wq   = (const float*)d_in[2];
    const float* bq   = (const float*)d_in[3];
    const float* Wk   = (const float*)d_in[4];
    const float* bk   = (const float*)d_in[5];
    const float* proj = (const float*)d_in[6];
    const float* Wm   = (const float*)d_in[7];
    const float* bm   = (const float*)d_in[8];
    const float* W1   = (const float*)d_in[9];
    const float* b1   = (const float*)d_in[10];
    const float* gam  = (const float*)d_in[11];
    const float* bet  = (const float*)d_in[12];
    const float* mu   = (const float*)d_in[13];
    const float* var  = (const float*)d_in[14];
    const float* W2   = (const float*)d_in[15];
    const float* b2   = (const float*)d_in[16];
    float* out = (float*)d_out;
    unsigned short* ws = (unsigned short*)d_ws;

    const long long E = 16777216LL;  // 4*4096*1024
    unsigned short* xt  = ws;
    unsigned short* st  = xt + E;
    unsigned short* qt  = st + E;
    unsigned short* kc  = qt + E;
    unsigned short* ht  = kc + E;
    unsigned short* pT  = ht + 2 * E;
    unsigned short* kpb = pT + 524288;
    unsigned short* wqb = kpb + 524288;
    unsigned short* wkb = wqb + 1048576;
    unsigned short* wmb = wkb + 1048576;
    unsigned short* w1b = wmb + 1048576;
    unsigned short* w2b = w1b + 4194304;
    float* bqp = (float*)(w2b + 2097152);
    float* bkp = bqp + 1024;
    float* kpacc = (float*)ht;  // kp split-K partials alias ht (not yet live)

    cvt_transpose_xs<<<dim3(128, 32, 8), 256, 0, stream>>>(x, srcp, xt, st);
    cvt_transpose<<<dim3(4, 128, 1), 256, 0, stream>>>(proj, pT, 4096, 128);
    prep_weights<<<9220, 256, 0, stream>>>(Wq, Wk, Wm, W1, W2, bq, bk,
                                           wqb, wkb, wmb, w1b, w2b, bqp, bkp);

    // q = Wq @ x           (M=4096 seq, N'=1024 out-ch, K=1024)
    gemm256<1024, 1024, 1024, 1024, false><<<dim3(4, 16, 4), 512, 0, stream>>>(
        xt, nullptr, 1024, wqb, qt, nullptr,
        4096LL * 1024, 0LL, 4096LL * 1024, nullptr, bqp,
        nullptr, nullptr, nullptr, nullptr);
    // kc = Wk @ source     (M=1024 out-ch, N'=4096 seq, K=1024)
    gemm256<1024, 1024, 4096, 1024, false><<<dim3(16, 4, 4), 512, 0, stream>>>(
        wkb, nullptr, 1024, st, kc, nullptr,
        0LL, 4096LL * 1024, 1024LL * 4096, bkp, nullptr,
        nullptr, nullptr, nullptr, nullptr);
    // kp projection: N'=128 too narrow for the 256-tile — keep 128-tile split-K.
    gemm_bt<4096, 4096, 128, 4096, 8, false><<<dim3(1, 8, 32), 256, 0, stream>>>(
        kc, nullptr, 4096, pT, nullptr, kpacc,
        1024LL * 4096, 0LL, 1024LL * 128, nullptr, nullptr,
        nullptr, nullptr, nullptr, nullptr);
    reduce_kp<<<512, 256, 0, stream>>>(kpacc, kpb);
    attn_fused<<<dim3(32, 16, 4), 256, 0, stream>>>(qt, kpb, qt);
    // merge                (M=4096 seq, N'=1024, K=1024)
    gemm256<1024, 1024, 1024, 1024, false><<<dim3(4, 16, 4), 512, 0, stream>>>(
        qt, nullptr, 1024, wmb, st, nullptr,
        4096LL * 1024, 0LL, 4096LL * 1024, nullptr, bm,
        nullptr, nullptr, nullptr, nullptr);
    // mlp1 + BN + ReLU     (M=4096, N'=2048, K=2048 concat)
    gemm256<1024, 2048, 2048, 2048, true><<<dim3(8, 16, 4), 512, 0, stream>>>(
        xt, st, 1024, w1b, ht, nullptr,
        4096LL * 1024, 0LL, 4096LL * 2048, nullptr, b1,
        gam, bet, mu, var);
    // mlp2 -> f32 out      (M=1024 out-ch, N'=4096 seq, K=2048)
    gemm256<2048, 2048, 4096, 2048, false><<<dim3(16, 4, 4), 512, 0, stream>>>(
        w2b, nullptr, 2048, ht, nullptr, out,
        0LL, 4096LL * 2048, 1024LL * 4096, b2, nullptr,
        nullptr, nullptr, nullptr, nullptr);
}

// Round 2
// 619.719 us; speedup vs baseline: 1.1731x; 1.0776x over previous
//
#include <hip/hip_runtime.h>
#include <stdint.h>

typedef __bf16 bf16x8 __attribute__((ext_vector_type(8)));
typedef float f32x4 __attribute__((ext_vector_type(4)));

__device__ __forceinline__ unsigned short f2bf(float f) {
    union { float f; uint32_t i; } v;
    v.f = f;
    uint32_t x = v.i;
    return (unsigned short)((x + 0x7FFFu + ((x >> 16) & 1u)) >> 16);  // RNE
}

// async global->LDS, 16B per lane. LDS dest is wave-uniform base + lane*16;
// the GLOBAL source address is per-lane free (this is what enables swizzling).
typedef __attribute__((address_space(3))) unsigned int lds_u32;
typedef __attribute__((address_space(1))) const unsigned int glob_u32;
__device__ __forceinline__ void gld16(const unsigned short* g, unsigned short* l) {
    __builtin_amdgcn_global_load_lds((glob_u32*)g, (lds_u32*)l, 16, 0, 0);
}

// ---------------------------------------------------------------------------
// All weight prep in ONE launch (range-dispatch on blockIdx.x, 9220 blocks).
// ---------------------------------------------------------------------------
__global__ __launch_bounds__(256) void prep_weights(
    const float* __restrict__ Wq, const float* __restrict__ Wk,
    const float* __restrict__ Wm, const float* __restrict__ W1,
    const float* __restrict__ W2, const float* __restrict__ bq,
    const float* __restrict__ bk,
    unsigned short* __restrict__ wqb, unsigned short* __restrict__ wkb,
    unsigned short* __restrict__ wmb, unsigned short* __restrict__ w1b,
    unsigned short* __restrict__ w2b, float* __restrict__ bqp,
    float* __restrict__ bkp)
{
    const int b = blockIdx.x, t = threadIdx.x;
    if (b < 2048) {
        const float* in = (b < 1024) ? Wq : Wk;
        unsigned short* out = (b < 1024) ? wqb : wkb;
        const int i = ((b & 1023) * 256 + t) * 4;
        const int row = i >> 10, col = i & 1023;
        const float4 v = *(const float4*)(in + ((row & 63) * 16 + (row >> 6)) * 1024 + col);
        out[i + 0] = f2bf(v.x); out[i + 1] = f2bf(v.y);
        out[i + 2] = f2bf(v.z); out[i + 3] = f2bf(v.w);
    } else if (b < 3072) {
        const int i = ((b - 2048) * 256 + t) * 4;
        const int row = i >> 10, c0 = i & 1023;
        const float* r = Wm + (size_t)row * 1024;
#pragma unroll
        for (int j = 0; j < 4; ++j) {
            const int c = c0 + j;
            wmb[i + j] = f2bf(r[(c & 63) * 16 + (c >> 6)]);
        }
    } else if (b < 7168) {
        const int i = ((b - 3072) * 256 + t) * 4;
        const float4 v = *(const float4*)(W1 + i);
        w1b[i + 0] = f2bf(v.x); w1b[i + 1] = f2bf(v.y);
        w1b[i + 2] = f2bf(v.z); w1b[i + 3] = f2bf(v.w);
    } else if (b < 9216) {
        const int i = ((b - 7168) * 256 + t) * 4;
        const float4 v = *(const float4*)(W2 + i);
        w2b[i + 0] = f2bf(v.x); w2b[i + 1] = f2bf(v.y);
        w2b[i + 2] = f2bf(v.z); w2b[i + 3] = f2bf(v.w);
    } else {
        const int o = (b - 9216) * 256 + t;
        const int src = (o & 63) * 16 + (o >> 6);
        bqp[o] = bq[src];
        bkp[o] = bk[src];
    }
}

// ---------------------------------------------------------------------------
// f32 [R][C] -> bf16 [C][R], batched over blockIdx.z (proj).
// ---------------------------------------------------------------------------
__global__ __launch_bounds__(256) void cvt_transpose(
    const float* __restrict__ in, unsigned short* __restrict__ out,
    int R, int C)
{
    __shared__ unsigned short tile[32][33];
    const size_t bo = (size_t)blockIdx.z * R * C;
    const int c0 = blockIdx.x * 32, r0 = blockIdx.y * 32;
    const int tx = threadIdx.x & 31, ty = threadIdx.x >> 5;
#pragma unroll
    for (int i = 0; i < 4; ++i)
        tile[ty + i * 8][tx] = f2bf(in[bo + (size_t)(r0 + ty + i * 8) * C + (c0 + tx)]);
    __syncthreads();
#pragma unroll
    for (int i = 0; i < 4; ++i)
        out[bo + (size_t)(c0 + ty + i * 8) * R + (r0 + tx)] = tile[tx][ty + i * 8];
}

// Fused x + source transpose: z = tensor*4 + batch.
__global__ __launch_bounds__(256) void cvt_transpose_xs(
    const float* __restrict__ x, const float* __restrict__ s,
    unsigned short* __restrict__ xt, unsigned short* __restrict__ st)
{
    __shared__ unsigned short tile[32][33];
    const int z = blockIdx.z;
    const float* in = (z < 4) ? x : s;
    unsigned short* out = (z < 4) ? xt : st;
    const size_t bo = (size_t)(z & 3) * 1024 * 4096;
    const int c0 = blockIdx.x * 32, r0 = blockIdx.y * 32;
    const int tx = threadIdx.x & 31, ty = threadIdx.x >> 5;
#pragma unroll
    for (int i = 0; i < 4; ++i)
        tile[ty + i * 8][tx] = f2bf(in[bo + (size_t)(r0 + ty + i * 8) * 4096 + (c0 + tx)]);
    __syncthreads();
#pragma unroll
    for (int i = 0; i < 4; ++i)
        out[bo + (size_t)(c0 + ty + i * 8) * 1024 + (r0 + tx)] = tile[tx][ty + i * 8];
}

// ---------------------------------------------------------------------------
// OLD 128x128 2-barrier GEMM. Kept ONLY for the kp projection (N'=128 < 256).
// ---------------------------------------------------------------------------
template<int LDA, int LDB, int LDC, int KD, int SPLIT, bool CONCAT>
__global__ __launch_bounds__(256) void gemm_bt(
    const unsigned short* __restrict__ A,
    const unsigned short* __restrict__ A2, int K1,
    const unsigned short* __restrict__ BT,
    unsigned short* __restrict__ C, float* __restrict__ Cf,
    long long strideA, long long strideB, long long strideC,
    const float* __restrict__ bias_m,
    const float* __restrict__ bias_n,
    const float* __restrict__ bn_g,
    const float* __restrict__ bn_b,
    const float* __restrict__ bn_mu,
    const float* __restrict__ bn_var)
{
    constexpr int KPB = KD / SPLIT;
    __shared__ __align__(16) unsigned short As[128 * 64];
    __shared__ __align__(16) unsigned short Bs[128 * 64];

    const int z = blockIdx.z;
    const int batch = z / SPLIT;
    const int kbase = (z % SPLIT) * KPB;
    const int m0 = blockIdx.y * 128, n0 = blockIdx.x * 128;
    const unsigned short* Ab  = A + (size_t)batch * strideA;
    const unsigned short* A2b = CONCAT ? A2 + (size_t)batch * strideA
                                       : (const unsigned short*)0;
    const unsigned short* Bb = BT + (size_t)batch * strideB;

    const int t = threadIdx.x;
    const int lane = t & 63, wid = t >> 6;
    const int wm = wid >> 1, wn = wid & 1;
    const int r16 = lane & 15, quad = lane >> 4;

    f32x4 acc[4][4];
    const f32x4 zf = {0.f, 0.f, 0.f, 0.f};
#pragma unroll
    for (int i = 0; i < 4; ++i)
#pragma unroll
        for (int j = 0; j < 4; ++j) acc[i][j] = zf;

    for (int kt = kbase; kt < kbase + KPB; kt += 64) {
        const unsigned short* Asrc = Ab;
        int kk = kt;
        if (CONCAT && kt >= K1) { Asrc = A2b; kk = kt - K1; }
#pragma unroll
        for (int i = 0; i < 4; ++i) {
            const int p = i * 256 + t;
            const int row = p >> 3, slot = p & 7;
            const int kc = (slot ^ (row & 7)) * 8;
            gld16(&Asrc[(size_t)(m0 + row) * LDA + kk + kc], &As[p * 8]);
            gld16(&Bb[(size_t)(n0 + row) * LDB + kt + kc], &Bs[p * 8]);
        }
        __syncthreads();
#pragma unroll
        for (int s = 0; s < 2; ++s) {
            bf16x8 af[4], bfb[4];
#pragma unroll
            for (int i = 0; i < 4; ++i) {
                const int ra = wm * 64 + i * 16 + r16;
                const int rb = wn * 64 + i * 16 + r16;
                af[i]  = *(const bf16x8*)&As[(ra * 8 + ((s * 4 + quad) ^ (ra & 7))) * 8];
                bfb[i] = *(const bf16x8*)&Bs[(rb * 8 + ((s * 4 + quad) ^ (rb & 7))) * 8];
            }
#pragma unroll
            for (int mi = 0; mi < 4; ++mi)
#pragma unroll
                for (int ni = 0; ni < 4; ++ni)
                    acc[mi][ni] = __builtin_amdgcn_mfma_f32_16x16x32_bf16(
                        af[mi], bfb[ni], acc[mi][ni], 0, 0, 0);
        }
        __syncthreads();
    }

    unsigned short* Cb = C ? C + (size_t)z * strideC : (unsigned short*)0;
    float* Cfb = Cf ? Cf + (size_t)z * strideC : (float*)0;
    const bool has_bn = (bn_g != 0);
#pragma unroll
    for (int ni = 0; ni < 4; ++ni) {
        const int gn = n0 + wn * 64 + ni * 16 + r16;
        const float addn = bias_n ? bias_n[gn] : 0.f;
        float g = 1.f, bb = 0.f, mu = 0.f, rstd = 1.f;
        if (has_bn) {
            g = bn_g[gn]; bb = bn_b[gn]; mu = bn_mu[gn];
            rstd = rsqrtf(bn_var[gn] + 1e-3f);
        }
#pragma unroll
        for (int mi = 0; mi < 4; ++mi) {
            const int gm0 = m0 + wm * 64 + mi * 16 + quad * 4;
#pragma unroll
            for (int r = 0; r < 4; ++r) {
                float v = acc[mi][ni][r] + addn;
                if (bias_m) v += bias_m[gm0 + r];
                if (has_bn) { v = g * (v - mu) * rstd + bb; v = fmaxf(v, 0.f); }
                const size_t idx = (size_t)(gm0 + r) * LDC + gn;
                if (Cfb) Cfb[idx] = v;
                else     Cb[idx]  = f2bf(v);
            }
        }
    }
}

// ---------------------------------------------------------------------------
// 256x256 8-phase GEMM (8 waves 2Mx4N, BK=64, dbuf LDS 128 KiB).
//
// FOUR distinct __shared__ objects (As0/As1/Bs0/Bs1): LLVM's waitcnt pass
// tracks global_load_lds as an LDS-DMA write and auto-inserts vmcnt waits
// before any may-aliasing ds_read. Distinct objects + the issue schedule
// below keep every gld >= 4 phases ahead of the next same-object ds_read,
// so the compiler's auto-waits match our manual vmcnt(6) (no added stalls).
//
// Unit schedule per tile X (units = 16KB, 2 gld/thread):
//   ph1: RD A(mh0) 8 + B(n01) 4;  issue U3(X+1) -> As_next   (read @ +4ph)
//   ph2: RD B(n23) 4
//   ph3: RD A(mh1) 8;             issue U1,U2(X+2) -> Bs_cur (read @ +6ph)
//   ph4:                          issue U0(X+2) -> As_cur    (read @ +5ph)
//        s_waitcnt vmcnt(6) -> tile X+1 fully staged, 3 units in flight.
// Each unit is issued only after its rows' last-read phase has closed
// (U0 rows read @ph1, B rows @ph1/2, U3 rows @ph3 -> all legal).
// ---------------------------------------------------------------------------
#define BAR   __builtin_amdgcn_s_barrier()
#define LGKM0 asm volatile("s_waitcnt lgkmcnt(0)" ::: "memory")
#define PRIO1 __builtin_amdgcn_s_setprio(1)
#define PRIO0 __builtin_amdgcn_s_setprio(0)

#define ST_A(dst, kt, i0, i1) do {                                          \
    const unsigned short* S_ = Ab; long long kk_ = (kt);                    \
    if (CONCAT && (kt) >= K1) { S_ = A2b; kk_ = (kt) - K1; }                \
    gld16(&S_[offA[i0] + kk_], (dst) + po[i0]);                             \
    gld16(&S_[offA[i1] + kk_], (dst) + po[i1]); } while (0)

#define ST_B(dst, kt, i0, i1) do {                                          \
    gld16(&Bb[offB[i0] + (kt)], (dst) + po[i0]);                            \
    gld16(&Bb[offB[i1] + (kt)], (dst) + po[i1]); } while (0)

#define RD_A(mh, AC) do {                                                   \
    _Pragma("unroll") for (int mi = 0; mi < 4; ++mi) {                      \
        const int ra = wm * 128 + (mh) * 64 + mi * 16 + r16;                \
        _Pragma("unroll") for (int ks = 0; ks < 2; ++ks) {                  \
            const int c_ = ks * 4 + quad;                                   \
            a[mi][ks] = *(const bf16x8*)&(AC)[(ra * 8 + (c_ ^ (ra & 7))) * 8]; \
        } } } while (0)

#define RD_B(np, BC) do {                                                   \
    _Pragma("unroll") for (int i = 0; i < 2; ++i) {                         \
        const int rb = wn * 64 + ((np) * 2 + i) * 16 + r16;                 \
        _Pragma("unroll") for (int ks = 0; ks < 2; ++ks) {                  \
            const int c_ = ks * 4 + quad;                                   \
            b[(np) * 2 + i][ks] = *(const bf16x8*)&(BC)[(rb * 8 + (c_ ^ (rb & 7))) * 8]; \
        } } } while (0)

#define MFMA_PH(mh, np) do {                                                \
    _Pragma("unroll") for (int mi = 0; mi < 4; ++mi)                        \
    _Pragma("unroll") for (int i = 0; i < 2; ++i)                           \
    _Pragma("unroll") for (int ks = 0; ks < 2; ++ks)                        \
        acc[(mh) * 4 + mi][(np) * 2 + i] =                                  \
            __builtin_amdgcn_mfma_f32_16x16x32_bf16(                        \
                a[mi][ks], b[(np) * 2 + i][ks],                             \
                acc[(mh) * 4 + mi][(np) * 2 + i], 0, 0, 0); } while (0)

#define TILE_BODY(XV, AC, BC, AN) do {                                      \
    const int kt1_ = ((XV) + 1) * 64, kt2_ = ((XV) + 2) * 64;               \
    const bool g1_ = ((XV) + 1) < nt, g2_ = ((XV) + 2) < nt;                \
    /* phase 1: A(mh0) 8 + B(n01) 4 reads; stage U3(X+1) -> next-buf A */   \
    RD_A(0, AC); RD_B(0, BC);                                               \
    if (g1_) ST_A(AN, kt1_, 1, 3);                                          \
    asm volatile("s_waitcnt lgkmcnt(8)" ::: "memory");                      \
    BAR; LGKM0; PRIO1; MFMA_PH(0, 0); PRIO0; BAR;                           \
    /* phase 2: B(n23) 4 reads (no staging) */                              \
    RD_B(1, BC);                                                            \
    BAR; LGKM0; PRIO1; MFMA_PH(0, 1); PRIO0; BAR;                           \
    /* phase 3: A(mh1) 8 reads; stage U1,U2(X+2) -> cur-buf B (dead) */     \
    RD_A(1, AC);                                                            \
    if (g2_) { ST_B(BC, kt2_, 0, 1); ST_B(BC, kt2_, 2, 3); }                \
    BAR; LGKM0; PRIO1; MFMA_PH(1, 1); PRIO0; BAR;                           \
    /* phase 4: stage U0(X+2) -> cur-buf A (dead); counted vmcnt */         \
    if (g2_) { ST_A(AC, kt2_, 0, 2);                                        \
               asm volatile("s_waitcnt vmcnt(6)" ::: "memory"); }           \
    else     { asm volatile("s_waitcnt vmcnt(0)" ::: "memory"); }           \
    BAR; LGKM0; PRIO1; MFMA_PH(1, 0); PRIO0; BAR;                           \
} while (0)

template<int LDA, int LDB, int LDC, int KD, bool CONCAT>
__global__ __launch_bounds__(512, 2) void gemm256(
    const unsigned short* __restrict__ A,
    const unsigned short* __restrict__ A2, int K1,
    const unsigned short* __restrict__ BT,
    unsigned short* __restrict__ C, float* __restrict__ Cf,
    long long strideA, long long strideB, long long strideC,
    const float* __restrict__ bias_m,
    const float* __restrict__ bias_n,
    const float* __restrict__ bn_g,
    const float* __restrict__ bn_b,
    const float* __restrict__ bn_mu,
    const float* __restrict__ bn_var)
{
    static_assert(KD % 128 == 0, "nt must be even");
    constexpr int nt = KD / 64;
    constexpr int TILE = 256 * 64;
    __shared__ __align__(16) unsigned short As0[TILE];
    __shared__ __align__(16) unsigned short As1[TILE];
    __shared__ __align__(16) unsigned short Bs0[TILE];
    __shared__ __align__(16) unsigned short Bs1[TILE];

    const int batch = blockIdx.z;
    // Bijective XCD-contiguous tile remap (all grids here have nwg % 8 == 0).
    const int gx = gridDim.x;
    const int nwg = gx * gridDim.y;
    int flat = blockIdx.y * gx + blockIdx.x;
    flat = (flat & 7) * (nwg >> 3) + (flat >> 3);
    const int n0 = (flat % gx) * 256;
    const int m0 = (flat / gx) * 256;

    const unsigned short* Ab  = A + (size_t)batch * strideA;
    const unsigned short* A2b = CONCAT ? A2 + (size_t)batch * strideA
                                       : (const unsigned short*)0;
    const unsigned short* Bb  = BT + (size_t)batch * strideB;

    const int t = threadIdx.x;
    const int lane = t & 63, wid = t >> 6;
    const int wm = wid >> 2, wn = wid & 3;       // 2 x 4 wave grid
    const int r16 = lane & 15, quad = lane >> 4;

    // Precomputed staging offsets (statically indexed only).
    long long offA[4], offB[4];
    int po[4];
#pragma unroll
    for (int i = 0; i < 4; ++i) {
        const int p = i * 512 + t, row = p >> 3;
        const int kc = ((p & 7) ^ (row & 7)) * 8;
        po[i] = p * 8;
        offA[i] = (long long)(m0 + row) * LDA + kc;
        offB[i] = (long long)(n0 + row) * LDB + kc;
    }

    f32x4 acc[8][4];
    const f32x4 zf = {0.f, 0.f, 0.f, 0.f};
#pragma unroll
    for (int i = 0; i < 8; ++i)
#pragma unroll
        for (int j = 0; j < 4; ++j) acc[i][j] = zf;

    bf16x8 a[4][2], b[4][2];

    // Prologue: all of T0, then U1,U2,U0(T1); vmcnt(6) => T0 fully staged,
    // exactly {U1,U2,U0(T1)} (6 loads) in flight -> steady-state invariant.
    ST_A(As0, 0, 0, 2);
    ST_B(Bs0, 0, 0, 1);
    ST_B(Bs0, 0, 2, 3);
    ST_A(As0, 0, 1, 3);
    ST_B(Bs1, 64, 0, 1);
    ST_B(Bs1, 64, 2, 3);
    ST_A(As1, 64, 0, 2);
    asm volatile("s_waitcnt vmcnt(6)" ::: "memory");
    BAR;

#pragma unroll 1
    for (int X2 = 0; X2 < nt; X2 += 2) {
        TILE_BODY(X2,     As0, Bs0, As1);
        TILE_BODY(X2 + 1, As1, Bs1, As0);
    }

    unsigned short* Cb = C ? C + (size_t)batch * strideC : (unsigned short*)0;
    float* Cfb = Cf ? Cf + (size_t)batch * strideC : (float*)0;
    const bool has_bn = (bn_g != 0);

    // Per-ni column params hoisted; ni innermost so both 32B halves of each
    // 64B line are written back-to-back (write-combining; bf16 C path).
    float addn4[4], g4[4], b4[4], mu4[4], rs4[4];
#pragma unroll
    for (int ni = 0; ni < 4; ++ni) {
        const int gn = n0 + wn * 64 + ni * 16 + r16;
        addn4[ni] = bias_n ? bias_n[gn] : 0.f;
        if (has_bn) {
            g4[ni] = bn_g[gn]; b4[ni] = bn_b[gn]; mu4[ni] = bn_mu[gn];
            rs4[ni] = rsqrtf(bn_var[gn] + 1e-3f);
        }
    }
#pragma unroll
    for (int mi = 0; mi < 8; ++mi) {
        const int gm0 = m0 + wm * 128 + mi * 16 + quad * 4;
#pragma unroll
        for (int r = 0; r < 4; ++r) {
            const float bm_ = bias_m ? bias_m[gm0 + r] : 0.f;
            const size_t rowb = (size_t)(gm0 + r) * LDC + n0 + wn * 64 + r16;
#pragma unroll
            for (int ni = 0; ni < 4; ++ni) {
                float v = acc[mi][ni][r] + addn4[ni] + bm_;
                if (has_bn) {
                    v = g4[ni] * (v - mu4[ni]) * rs4[ni] + b4[ni];
                    v = fmaxf(v, 0.f);
                }
                if (Cfb) Cfb[rowb + ni * 16] = v;
                else     Cb[rowb + ni * 16]  = f2bf(v);
            }
        }
    }
}

#undef TILE_BODY
#undef MFMA_PH
#undef RD_B
#undef RD_A
#undef ST_B
#undef ST_A
#undef PRIO0
#undef PRIO1
#undef LGKM0
#undef BAR

// kp split-K reduce: kpb[b][j] = bf16( sum_p acc[b*8+p][j] )
__global__ __launch_bounds__(256) void reduce_kp(
    const float* __restrict__ acc, unsigned short* __restrict__ kpb)
{
    const int j = (blockIdx.x * 256 + threadIdx.x) * 4;
    const int b = j >> 17, jj = j & 131071;
    const float* base = acc + (size_t)b * 8 * 131072 + jj;
    float4 s = *(const float4*)base;
#pragma unroll
    for (int p = 1; p < 8; ++p) {
        const float4 v = *(const float4*)(base + (size_t)p * 131072);
        s.x += v.x; s.y += v.y; s.z += v.z; s.w += v.w;
    }
    kpb[j + 0] = f2bf(s.x); kpb[j + 1] = f2bf(s.y);
    kpb[j + 2] = f2bf(s.z); kpb[j + 3] = f2bf(s.w);
}

// ---------------------------------------------------------------------------
// MFMA flash-attention (unchanged; channel order o' = h*64+dh).
// ---------------------------------------------------------------------------
__global__ __launch_bounds__(256) void attn_fused(
    const unsigned short* __restrict__ qT,
    const unsigned short* __restrict__ kp,
    unsigned short* __restrict__ msgT)
{
    constexpr int QS = 72, KS = 72, VS = 136, PS = 136;
    __shared__ __align__(16) unsigned short QKP[128 * QS + 128 * KS];
    __shared__ __align__(16) unsigned short Vs[64 * VS];
    unsigned short* Qs = QKP;
    unsigned short* Ks = QKP + 128 * QS;
    unsigned short* Ps = QKP;

    const int t = threadIdx.x;
    const int lane = t & 63, w = t >> 6;
    const int r16 = lane & 15, quad = lane >> 4;
    const int h = blockIdx.y, n0 = blockIdx.x * 128;
    const size_t b = blockIdx.z;

    const unsigned short* qbase = qT + (b * 4096 + n0) * 1024 + h * 64;
    const unsigned short* kbase = kp + (b * 1024 + h * 64) * 128;

#pragma unroll
    for (int i = 0; i < 4; ++i) {
        const int c = i * 256 + t;
        const int n = c >> 3, dh0 = (c & 7) * 8;
        *(int4*)&Qs[n * QS + dh0] = *(const int4*)&qbase[(size_t)n * 1024 + dh0];
    }
#pragma unroll
    for (int i = 0; i < 4; ++i) {
        const int c = i * 256 + t;
        const int kkq = c & 3, dh = (c >> 2) & 63, kkh = c >> 8;
        const int kk0 = kkh * 32 + kkq * 8;
        const bf16x8 v = *(const bf16x8*)&kbase[(size_t)dh * 128 + kk0];
        *(bf16x8*)&Vs[dh * VS + kk0] = v;
        const unsigned short* vs = (const unsigned short*)&v;
#pragma unroll
        for (int j = 0; j < 8; ++j) Ks[(kk0 + j) * KS + dh] = vs[j];
    }
    __syncthreads();

    f32x4 S[2][8];
    const f32x4 zf = {0.f, 0.f, 0.f, 0.f};
#pragma unroll
    for (int mi = 0; mi < 2; ++mi)
#pragma unroll
        for (int ni = 0; ni < 8; ++ni) S[mi][ni] = zf;

    bf16x8 aq[2][2];
#pragma unroll
    for (int mi = 0; mi < 2; ++mi)
#pragma unroll
        for (int ks = 0; ks < 2; ++ks)
            aq[mi][ks] = *(const bf16x8*)&Qs[(w * 32 + mi * 16 + r16) * QS + ks * 32 + quad * 8];
#pragma unroll
    for (int ni = 0; ni < 8; ++ni) {
        const bf16x8 b0 = *(const bf16x8*)&Ks[(ni * 16 + r16) * KS + quad * 8];
        const bf16x8 b1 = *(const bf16x8*)&Ks[(ni * 16 + r16) * KS + 32 + quad * 8];
#pragma unroll
        for (int mi = 0; mi < 2; ++mi) {
            S[mi][ni] = __builtin_amdgcn_mfma_f32_16x16x32_bf16(aq[mi][0], b0, S[mi][ni], 0, 0, 0);
            S[mi][ni] = __builtin_amdgcn_mfma_f32_16x16x32_bf16(aq[mi][1], b1, S[mi][ni], 0, 0, 0);
        }
    }

    __syncthreads();

    float linv[2][4];
#pragma unroll
    for (int mi = 0; mi < 2; ++mi) {
        float e[8][4];
        float rs0 = 0.f, rs1 = 0.f, rs2 = 0.f, rs3 = 0.f;
#pragma unroll
        for (int ni = 0; ni < 8; ++ni) {
            e[ni][0] = __expf(S[mi][ni][0] * 0.125f); rs0 += e[ni][0];
            e[ni][1] = __expf(S[mi][ni][1] * 0.125f); rs1 += e[ni][1];
            e[ni][2] = __expf(S[mi][ni][2] * 0.125f); rs2 += e[ni][2];
            e[ni][3] = __expf(S[mi][ni][3] * 0.125f); rs3 += e[ni][3];
        }
        float rs[4] = {rs0, rs1, rs2, rs3};
#pragma unroll
        for (int r = 0; r < 4; ++r) {
            float s = rs[r];
            s += __shfl_xor(s, 1); s += __shfl_xor(s, 2);
            s += __shfl_xor(s, 4); s += __shfl_xor(s, 8);
            linv[mi][r] = 1.f / s;
        }
#pragma unroll
        for (int ni = 0; ni < 8; ++ni)
#pragma unroll
            for (int r = 0; r < 4; ++r)
                Ps[(w * 32 + mi * 16 + quad * 4 + r) * PS + ni * 16 + r16] = f2bf(e[ni][r]);
    }
    __syncthreads();

    f32x4 O[2][4];
#pragma unroll
    for (int mi = 0; mi < 2; ++mi)
#pragma unroll
        for (int ni = 0; ni < 4; ++ni) O[mi][ni] = zf;

    bf16x8 ap[2][4];
#pragma unroll
    for (int mi = 0; mi < 2; ++mi)
#pragma unroll
        for (int ks = 0; ks < 4; ++ks)
            ap[mi][ks] = *(const bf16x8*)&Ps[(w * 32 + mi * 16 + r16) * PS + ks * 32 + quad * 8];
#pragma unroll
    for (int ni = 0; ni < 4; ++ni)
#pragma unroll
        for (int ks = 0; ks < 4; ++ks) {
            const bf16x8 bv = *(const bf16x8*)&Vs[(ni * 16 + r16) * VS + ks * 32 + quad * 8];
#pragma unroll
            for (int mi = 0; mi < 2; ++mi)
                O[mi][ni] = __builtin_amdgcn_mfma_f32_16x16x32_bf16(ap[mi][ks], bv, O[mi][ni], 0, 0, 0);
        }

    unsigned short* ob = msgT + (b * 4096 + n0) * 1024 + h * 64;
#pragma unroll
    for (int mi = 0; mi < 2; ++mi)
#pragma unroll
        for (int ni = 0; ni < 4; ++ni)
#pragma unroll
            for (int r = 0; r < 4; ++r)
                ob[(size_t)(w * 32 + mi * 16 + quad * 4 + r) * 1024 + ni * 16 + r16] =
                    f2bf(O[mi][ni][r] * linv[mi][r]);
}

// ---------------------------------------------------------------------------
extern "C" void kernel_launch(void* const* d_in, const int* in_sizes, int n_in,
                              void* d_out, int out_size, void* d_ws, size_t ws_size,
                              hipStream_t stream)
{
    (void)in_sizes; (void)n_in; (void)out_size; (void)ws_size;
    const float* x    = (const float*)d_in[0];
    const float* srcp = (const float*)d_in[1];
    const float* Wq   = (const float*)d_in[2];
    const float* bq   = (const float*)d_in[3];
    const float* Wk   = (const float*)d_in[4];
    const float* bk   = (const float*)d_in[5];
    const float* proj = (const float*)d_in[6];
    const float* Wm   = (const float*)d_in[7];
    const float* bm   = (const float*)d_in[8];
    const float* W1   = (const float*)d_in[9];
    const float* b1   = (const float*)d_in[10];
    const float* gam  = (const float*)d_in[11];
    const float* bet  = (const float*)d_in[12];
    const float* mu   = (const float*)d_in[13];
    const float* var  = (const float*)d_in[14];
    const float* W2   = (const float*)d_in[15];
    const float* b2   = (const float*)d_in[16];
    float* out = (float*)d_out;
    unsigned short* ws = (unsigned short*)d_ws;

    const long long E = 16777216LL;  // 4*4096*1024
    unsigned short* xt  = ws;
    unsigned short* st  = xt + E;
    unsigned short* qt  = st + E;
    unsigned short* kc  = qt + E;
    unsigned short* ht  = kc + E;
    unsigned short* pT  = ht + 2 * E;
    unsigned short* kpb = pT + 524288;
    unsigned short* wqb = kpb + 524288;
    unsigned short* wkb = wqb + 1048576;
    unsigned short* wmb = wkb + 1048576;
    unsigned short* w1b = wmb + 1048576;
    unsigned short* w2b = w1b + 4194304;
    float* bqp = (float*)(w2b + 2097152);
    float* bkp = bqp + 1024;
    float* kpacc = (float*)ht;  // kp split-K partials alias ht (not yet live)

    cvt_transpose_xs<<<dim3(128, 32, 8), 256, 0, stream>>>(x, srcp, xt, st);
    cvt_transpose<<<dim3(4, 128, 1), 256, 0, stream>>>(proj, pT, 4096, 128);
    prep_weights<<<9220, 256, 0, stream>>>(Wq, Wk, Wm, W1, W2, bq, bk,
                                           wqb, wkb, wmb, w1b, w2b, bqp, bkp);

    // q = Wq @ x           (M=4096 seq, N'=1024 out-ch, K=1024)
    gemm256<1024, 1024, 1024, 1024, false><<<dim3(4, 16, 4), 512, 0, stream>>>(
        xt, nullptr, 1024, wqb, qt, nullptr,
        4096LL * 1024, 0LL, 4096LL * 1024, nullptr, bqp,
        nullptr, nullptr, nullptr, nullptr);
    // kc = Wk @ source     (M=1024 out-ch, N'=4096 seq, K=1024)
    gemm256<1024, 1024, 4096, 1024, false><<<dim3(16, 4, 4), 512, 0, stream>>>(
        wkb, nullptr, 1024, st, kc, nullptr,
        0LL, 4096LL * 1024, 1024LL * 4096, bkp, nullptr,
        nullptr, nullptr, nullptr, nullptr);
    // kp projection: N'=128 too narrow for the 256-tile — keep 128-tile split-K.
    gemm_bt<4096, 4096, 128, 4096, 8, false><<<dim3(1, 8, 32), 256, 0, stream>>>(
        kc, nullptr, 4096, pT, nullptr, kpacc,
        1024LL * 4096, 0LL, 1024LL * 128, nullptr, nullptr,
        nullptr, nullptr, nullptr, nullptr);
    reduce_kp<<<512, 256, 0, stream>>>(kpacc, kpb);
    attn_fused<<<dim3(32, 16, 4), 256, 0, stream>>>(qt, kpb, qt);
    // merge                (M=4096 seq, N'=1024, K=1024)
    gemm256<1024, 1024, 1024, 1024, false><<<dim3(4, 16, 4), 512, 0, stream>>>(
        qt, nullptr, 1024, wmb, st, nullptr,
        4096LL * 1024, 0LL, 4096LL * 1024, nullptr, bm,
        nullptr, nullptr, nullptr, nullptr);
    // mlp1 + BN + ReLU     (M=4096, N'=2048, K=2048 concat)
    gemm256<1024, 2048, 2048, 2048, true><<<dim3(8, 16, 4), 512, 0, stream>>>(
        xt, st, 1024, w1b, ht, nullptr,
        4096LL * 1024, 0LL, 4096LL * 2048, nullptr, b1,
        gam, bet, mu, var);
    // mlp2 -> f32 out      (M=1024 out-ch, N'=4096 seq, K=2048)
    gemm256<2048, 2048, 4096, 2048, false><<<dim3(16, 4, 4), 512, 0, stream>>>(
        w2b, nullptr, 2048, ht, nullptr, out,
        0LL, 4096LL * 2048, 1024LL * 4096, b2, nullptr,
        nullptr, nullptr, nullptr, nullptr);
}

// Round 3
// 618.430 us; speedup vs baseline: 1.1756x; 1.0021x over previous
//
#include <hip/hip_runtime.h>
#include <stdint.h>

typedef __bf16 bf16x8 __attribute__((ext_vector_type(8)));
typedef float f32x4 __attribute__((ext_vector_type(4)));

__device__ __forceinline__ unsigned short f2bf(float f) {
    union { float f; uint32_t i; } v;
    v.f = f;
    uint32_t x = v.i;
    return (unsigned short)((x + 0x7FFFu + ((x >> 16) & 1u)) >> 16);  // RNE
}

// async global->LDS, 16B per lane. LDS dest is wave-uniform base + lane*16;
// the GLOBAL source address is per-lane free (this is what enables swizzling).
typedef __attribute__((address_space(3))) unsigned int lds_u32;
typedef __attribute__((address_space(1))) const unsigned int glob_u32;
__device__ __forceinline__ void gld16(const unsigned short* g, unsigned short* l) {
    __builtin_amdgcn_global_load_lds((glob_u32*)g, (lds_u32*)l, 16, 0, 0);
}

// ---------------------------------------------------------------------------
// All weight prep in ONE launch (range-dispatch on blockIdx.x, 9220 blocks).
// ---------------------------------------------------------------------------
__global__ __launch_bounds__(256) void prep_weights(
    const float* __restrict__ Wq, const float* __restrict__ Wk,
    const float* __restrict__ Wm, const float* __restrict__ W1,
    const float* __restrict__ W2, const float* __restrict__ bq,
    const float* __restrict__ bk,
    unsigned short* __restrict__ wqb, unsigned short* __restrict__ wkb,
    unsigned short* __restrict__ wmb, unsigned short* __restrict__ w1b,
    unsigned short* __restrict__ w2b, float* __restrict__ bqp,
    float* __restrict__ bkp)
{
    const int b = blockIdx.x, t = threadIdx.x;
    if (b < 2048) {
        const float* in = (b < 1024) ? Wq : Wk;
        unsigned short* out = (b < 1024) ? wqb : wkb;
        const int i = ((b & 1023) * 256 + t) * 4;
        const int row = i >> 10, col = i & 1023;
        const float4 v = *(const float4*)(in + ((row & 63) * 16 + (row >> 6)) * 1024 + col);
        out[i + 0] = f2bf(v.x); out[i + 1] = f2bf(v.y);
        out[i + 2] = f2bf(v.z); out[i + 3] = f2bf(v.w);
    } else if (b < 3072) {
        const int i = ((b - 2048) * 256 + t) * 4;
        const int row = i >> 10, c0 = i & 1023;
        const float* r = Wm + (size_t)row * 1024;
#pragma unroll
        for (int j = 0; j < 4; ++j) {
            const int c = c0 + j;
            wmb[i + j] = f2bf(r[(c & 63) * 16 + (c >> 6)]);
        }
    } else if (b < 7168) {
        const int i = ((b - 3072) * 256 + t) * 4;
        const float4 v = *(const float4*)(W1 + i);
        w1b[i + 0] = f2bf(v.x); w1b[i + 1] = f2bf(v.y);
        w1b[i + 2] = f2bf(v.z); w1b[i + 3] = f2bf(v.w);
    } else if (b < 9216) {
        const int i = ((b - 7168) * 256 + t) * 4;
        const float4 v = *(const float4*)(W2 + i);
        w2b[i + 0] = f2bf(v.x); w2b[i + 1] = f2bf(v.y);
        w2b[i + 2] = f2bf(v.z); w2b[i + 3] = f2bf(v.w);
    } else {
        const int o = (b - 9216) * 256 + t;
        const int src = (o & 63) * 16 + (o >> 6);
        bqp[o] = bq[src];
        bkp[o] = bk[src];
    }
}

// ---------------------------------------------------------------------------
// f32 [R][C] -> bf16 [C][R], batched over blockIdx.z (proj).
// ---------------------------------------------------------------------------
__global__ __launch_bounds__(256) void cvt_transpose(
    const float* __restrict__ in, unsigned short* __restrict__ out,
    int R, int C)
{
    __shared__ unsigned short tile[32][33];
    const size_t bo = (size_t)blockIdx.z * R * C;
    const int c0 = blockIdx.x * 32, r0 = blockIdx.y * 32;
    const int tx = threadIdx.x & 31, ty = threadIdx.x >> 5;
#pragma unroll
    for (int i = 0; i < 4; ++i)
        tile[ty + i * 8][tx] = f2bf(in[bo + (size_t)(r0 + ty + i * 8) * C + (c0 + tx)]);
    __syncthreads();
#pragma unroll
    for (int i = 0; i < 4; ++i)
        out[bo + (size_t)(c0 + ty + i * 8) * R + (r0 + tx)] = tile[tx][ty + i * 8];
}

// Fused x + source transpose: z = tensor*4 + batch.
__global__ __launch_bounds__(256) void cvt_transpose_xs(
    const float* __restrict__ x, const float* __restrict__ s,
    unsigned short* __restrict__ xt, unsigned short* __restrict__ st)
{
    __shared__ unsigned short tile[32][33];
    const int z = blockIdx.z;
    const float* in = (z < 4) ? x : s;
    unsigned short* out = (z < 4) ? xt : st;
    const size_t bo = (size_t)(z & 3) * 1024 * 4096;
    const int c0 = blockIdx.x * 32, r0 = blockIdx.y * 32;
    const int tx = threadIdx.x & 31, ty = threadIdx.x >> 5;
#pragma unroll
    for (int i = 0; i < 4; ++i)
        tile[ty + i * 8][tx] = f2bf(in[bo + (size_t)(r0 + ty + i * 8) * 4096 + (c0 + tx)]);
    __syncthreads();
#pragma unroll
    for (int i = 0; i < 4; ++i)
        out[bo + (size_t)(c0 + ty + i * 8) * 1024 + (r0 + tx)] = tile[tx][ty + i * 8];
}

// ---------------------------------------------------------------------------
// OLD 128x128 2-barrier GEMM. Kept ONLY for the kp projection (N'=128 < 256).
// ---------------------------------------------------------------------------
template<int LDA, int LDB, int LDC, int KD, int SPLIT, bool CONCAT>
__global__ __launch_bounds__(256) void gemm_bt(
    const unsigned short* __restrict__ A,
    const unsigned short* __restrict__ A2, int K1,
    const unsigned short* __restrict__ BT,
    unsigned short* __restrict__ C, float* __restrict__ Cf,
    long long strideA, long long strideB, long long strideC,
    const float* __restrict__ bias_m,
    const float* __restrict__ bias_n,
    const float* __restrict__ bn_g,
    const float* __restrict__ bn_b,
    const float* __restrict__ bn_mu,
    const float* __restrict__ bn_var)
{
    constexpr int KPB = KD / SPLIT;
    __shared__ __align__(16) unsigned short As[128 * 64];
    __shared__ __align__(16) unsigned short Bs[128 * 64];

    const int z = blockIdx.z;
    const int batch = z / SPLIT;
    const int kbase = (z % SPLIT) * KPB;
    const int m0 = blockIdx.y * 128, n0 = blockIdx.x * 128;
    const unsigned short* Ab  = A + (size_t)batch * strideA;
    const unsigned short* A2b = CONCAT ? A2 + (size_t)batch * strideA
                                       : (const unsigned short*)0;
    const unsigned short* Bb = BT + (size_t)batch * strideB;

    const int t = threadIdx.x;
    const int lane = t & 63, wid = t >> 6;
    const int wm = wid >> 1, wn = wid & 1;
    const int r16 = lane & 15, quad = lane >> 4;

    f32x4 acc[4][4];
    const f32x4 zf = {0.f, 0.f, 0.f, 0.f};
#pragma unroll
    for (int i = 0; i < 4; ++i)
#pragma unroll
        for (int j = 0; j < 4; ++j) acc[i][j] = zf;

    for (int kt = kbase; kt < kbase + KPB; kt += 64) {
        const unsigned short* Asrc = Ab;
        int kk = kt;
        if (CONCAT && kt >= K1) { Asrc = A2b; kk = kt - K1; }
#pragma unroll
        for (int i = 0; i < 4; ++i) {
            const int p = i * 256 + t;
            const int row = p >> 3, slot = p & 7;
            const int kc = (slot ^ (row & 7)) * 8;
            gld16(&Asrc[(size_t)(m0 + row) * LDA + kk + kc], &As[p * 8]);
            gld16(&Bb[(size_t)(n0 + row) * LDB + kt + kc], &Bs[p * 8]);
        }
        __syncthreads();
#pragma unroll
        for (int s = 0; s < 2; ++s) {
            bf16x8 af[4], bfb[4];
#pragma unroll
            for (int i = 0; i < 4; ++i) {
                const int ra = wm * 64 + i * 16 + r16;
                const int rb = wn * 64 + i * 16 + r16;
                af[i]  = *(const bf16x8*)&As[(ra * 8 + ((s * 4 + quad) ^ (ra & 7))) * 8];
                bfb[i] = *(const bf16x8*)&Bs[(rb * 8 + ((s * 4 + quad) ^ (rb & 7))) * 8];
            }
#pragma unroll
            for (int mi = 0; mi < 4; ++mi)
#pragma unroll
                for (int ni = 0; ni < 4; ++ni)
                    acc[mi][ni] = __builtin_amdgcn_mfma_f32_16x16x32_bf16(
                        af[mi], bfb[ni], acc[mi][ni], 0, 0, 0);
        }
        __syncthreads();
    }

    unsigned short* Cb = C ? C + (size_t)z * strideC : (unsigned short*)0;
    float* Cfb = Cf ? Cf + (size_t)z * strideC : (float*)0;
    const bool has_bn = (bn_g != 0);
#pragma unroll
    for (int ni = 0; ni < 4; ++ni) {
        const int gn = n0 + wn * 64 + ni * 16 + r16;
        const float addn = bias_n ? bias_n[gn] : 0.f;
        float g = 1.f, bb = 0.f, mu = 0.f, rstd = 1.f;
        if (has_bn) {
            g = bn_g[gn]; bb = bn_b[gn]; mu = bn_mu[gn];
            rstd = rsqrtf(bn_var[gn] + 1e-3f);
        }
#pragma unroll
        for (int mi = 0; mi < 4; ++mi) {
            const int gm0 = m0 + wm * 64 + mi * 16 + quad * 4;
#pragma unroll
            for (int r = 0; r < 4; ++r) {
                float v = acc[mi][ni][r] + addn;
                if (bias_m) v += bias_m[gm0 + r];
                if (has_bn) { v = g * (v - mu) * rstd + bb; v = fmaxf(v, 0.f); }
                const size_t idx = (size_t)(gm0 + r) * LDC + gn;
                if (Cfb) Cfb[idx] = v;
                else     Cb[idx]  = f2bf(v);
            }
        }
    }
}

// ---------------------------------------------------------------------------
// 256x256 GEMM, TWO-phase K-step (8 waves 2Mx4N, BK=64, dbuf LDS 128 KiB).
//
// v3: 4 phases -> 2 phases per K-tile. Rounds 1-2 showed the 4-phase
// schedule stuck at MfmaUtil ~38% (vs m201's 62%) with 0 bank conflicts
// and counted vmcnt -- the residual ~2400 cyc/K-tile is attributed to
// 8 workgroup barriers + 4 lgkmcnt(0) drains per K-tile at 1 block/CU
// (no co-resident block to cover sync shadows; unified-reg budget caps
// occupancy at 2 waves/SIMD). 2 phases halve the sync count and double
// the setprio-protected MFMA cluster length (32 MFMA).
//
//   phA: RD A(mh0)[8] + B(all)[8];  stage U0,U1,U2(X+1)->next buf [6 gld]
//        vmcnt(6)  (completes U3(X), issued 1 phase earlier)
//        BAR; lgkmcnt(0); prio1; MFMA (0,0)+(0,1) [32]; prio0; BAR
//   phB: RD A(mh1)[8];              stage U3(X+1)->next buf [2 gld]
//        vmcnt(2)  (completes U0,U1,U2(X+1), issued 1 phase earlier)
//        BAR; lgkmcnt(0); prio1; MFMA (1,1)+(1,0) [32]; prio0; BAR
// Steady state: 2-8 loads in flight; never drains to 0 mid-loop.
// ---------------------------------------------------------------------------
#define BAR   __builtin_amdgcn_s_barrier()
#define LGKM0 asm volatile("s_waitcnt lgkmcnt(0)" ::: "memory")
#define PRIO1 __builtin_amdgcn_s_setprio(1)
#define PRIO0 __builtin_amdgcn_s_setprio(0)

#define ST_A(dst, kt, i0, i1) do {                                          \
    const unsigned short* S_ = Ab; long long kk_ = (kt);                    \
    if (CONCAT && (kt) >= K1) { S_ = A2b; kk_ = (kt) - K1; }                \
    gld16(&S_[offA[i0] + kk_], (dst) + po[i0]);                             \
    gld16(&S_[offA[i1] + kk_], (dst) + po[i1]); } while (0)

#define ST_B(dst, kt, i0, i1) do {                                          \
    gld16(&Bb[offB[i0] + (kt)], (dst) + po[i0]);                            \
    gld16(&Bb[offB[i1] + (kt)], (dst) + po[i1]); } while (0)

#define RD_A(mh, AC) do {                                                   \
    _Pragma("unroll") for (int mi = 0; mi < 4; ++mi) {                      \
        const int ra = wm * 128 + (mh) * 64 + mi * 16 + r16;                \
        _Pragma("unroll") for (int ks = 0; ks < 2; ++ks) {                  \
            const int c_ = ks * 4 + quad;                                   \
            a[mi][ks] = *(const bf16x8*)&(AC)[(ra * 8 + (c_ ^ (ra & 7))) * 8]; \
        } } } while (0)

#define RD_B(np, BC) do {                                                   \
    _Pragma("unroll") for (int i = 0; i < 2; ++i) {                         \
        const int rb = wn * 64 + ((np) * 2 + i) * 16 + r16;                 \
        _Pragma("unroll") for (int ks = 0; ks < 2; ++ks) {                  \
            const int c_ = ks * 4 + quad;                                   \
            b[(np) * 2 + i][ks] = *(const bf16x8*)&(BC)[(rb * 8 + (c_ ^ (rb & 7))) * 8]; \
        } } } while (0)

#define MFMA_PH(mh, np) do {                                                \
    _Pragma("unroll") for (int mi = 0; mi < 4; ++mi)                        \
    _Pragma("unroll") for (int i = 0; i < 2; ++i)                           \
    _Pragma("unroll") for (int ks = 0; ks < 2; ++ks)                        \
        acc[(mh) * 4 + mi][(np) * 2 + i] =                                  \
            __builtin_amdgcn_mfma_f32_16x16x32_bf16(                        \
                a[mi][ks], b[(np) * 2 + i][ks],                             \
                acc[(mh) * 4 + mi][(np) * 2 + i], 0, 0, 0); } while (0)

#define TILE_BODY(XV, AC, BC, AN, BN_) do {                                 \
    const int kt1_ = ((XV) + 1) * 64;                                       \
    const bool g1_ = ((XV) + 1) < nt;                                       \
    /* phase A: A(mh0)+all-B reads; stage U0,U1,U2(X+1) -> next buf */      \
    RD_A(0, AC); RD_B(0, BC); RD_B(1, BC);                                  \
    if (g1_) { ST_A(AN, kt1_, 0, 2); ST_B(BN_, kt1_, 0, 1);                 \
               ST_B(BN_, kt1_, 2, 3);                                       \
               asm volatile("s_waitcnt vmcnt(6)" ::: "memory"); }           \
    else     { asm volatile("s_waitcnt vmcnt(0)" ::: "memory"); }           \
    BAR; LGKM0; PRIO1; MFMA_PH(0, 0); MFMA_PH(0, 1); PRIO0; BAR;            \
    /* phase B: A(mh1) reads; stage U3(X+1) -> next buf */                  \
    RD_A(1, AC);                                                            \
    if (g1_) { ST_A(AN, kt1_, 1, 3);                                        \
               asm volatile("s_waitcnt vmcnt(2)" ::: "memory"); }           \
    else     { asm volatile("s_waitcnt vmcnt(0)" ::: "memory"); }           \
    BAR; LGKM0; PRIO1; MFMA_PH(1, 1); MFMA_PH(1, 0); PRIO0; BAR;            \
} while (0)

template<int LDA, int LDB, int LDC, int KD, bool CONCAT>
__global__ __launch_bounds__(512, 2) void gemm256(
    const unsigned short* __restrict__ A,
    const unsigned short* __restrict__ A2, int K1,
    const unsigned short* __restrict__ BT,
    unsigned short* __restrict__ C, float* __restrict__ Cf,
    long long strideA, long long strideB, long long strideC,
    const float* __restrict__ bias_m,
    const float* __restrict__ bias_n,
    const float* __restrict__ bn_g,
    const float* __restrict__ bn_b,
    const float* __restrict__ bn_mu,
    const float* __restrict__ bn_var)
{
    static_assert(KD % 128 == 0, "nt must be even");
    constexpr int nt = KD / 64;
    constexpr int TILE = 256 * 64;
    __shared__ __align__(16) unsigned short As0[TILE];
    __shared__ __align__(16) unsigned short As1[TILE];
    __shared__ __align__(16) unsigned short Bs0[TILE];
    __shared__ __align__(16) unsigned short Bs1[TILE];

    const int batch = blockIdx.z;
    // Bijective XCD-contiguous tile remap (all grids here have nwg % 8 == 0).
    const int gx = gridDim.x;
    const int nwg = gx * gridDim.y;
    int flat = blockIdx.y * gx + blockIdx.x;
    flat = (flat & 7) * (nwg >> 3) + (flat >> 3);
    const int n0 = (flat % gx) * 256;
    const int m0 = (flat / gx) * 256;

    const unsigned short* Ab  = A + (size_t)batch * strideA;
    const unsigned short* A2b = CONCAT ? A2 + (size_t)batch * strideA
                                       : (const unsigned short*)0;
    const unsigned short* Bb  = BT + (size_t)batch * strideB;

    const int t = threadIdx.x;
    const int lane = t & 63, wid = t >> 6;
    const int wm = wid >> 2, wn = wid & 3;       // 2 x 4 wave grid
    const int r16 = lane & 15, quad = lane >> 4;

    // Precomputed staging offsets (statically indexed only).
    long long offA[4], offB[4];
    int po[4];
#pragma unroll
    for (int i = 0; i < 4; ++i) {
        const int p = i * 512 + t, row = p >> 3;
        const int kc = ((p & 7) ^ (row & 7)) * 8;
        po[i] = p * 8;
        offA[i] = (long long)(m0 + row) * LDA + kc;
        offB[i] = (long long)(n0 + row) * LDB + kc;
    }

    f32x4 acc[8][4];
    const f32x4 zf = {0.f, 0.f, 0.f, 0.f};
#pragma unroll
    for (int i = 0; i < 8; ++i)
#pragma unroll
        for (int j = 0; j < 4; ++j) acc[i][j] = zf;

    bf16x8 a[4][2], b[4][2];

    // Prologue: all 4 units of T0 (queue order U0,U1,U2,U3); vmcnt(2)
    // completes U0,U1,U2 (needed by phA(0)); U3(T0) stays in flight and is
    // completed by phA(0)'s vmcnt(6) before phB(0) reads it.
    ST_A(As0, 0, 0, 2);
    ST_B(Bs0, 0, 0, 1);
    ST_B(Bs0, 0, 2, 3);
    ST_A(As0, 0, 1, 3);
    asm volatile("s_waitcnt vmcnt(2)" ::: "memory");
    BAR;

#pragma unroll 1
    for (int X2 = 0; X2 < nt; X2 += 2) {
        TILE_BODY(X2,     As0, Bs0, As1, Bs1);
        TILE_BODY(X2 + 1, As1, Bs1, As0, Bs0);
    }

    unsigned short* Cb = C ? C + (size_t)batch * strideC : (unsigned short*)0;
    float* Cfb = Cf ? Cf + (size_t)batch * strideC : (float*)0;
    const bool has_bn = (bn_g != 0);

    // Per-ni column params hoisted; ni innermost so both 32B halves of each
    // 64B line are written back-to-back (write-combining; bf16 C path).
    float addn4[4], g4[4], b4[4], mu4[4], rs4[4];
#pragma unroll
    for (int ni = 0; ni < 4; ++ni) {
        const int gn = n0 + wn * 64 + ni * 16 + r16;
        addn4[ni] = bias_n ? bias_n[gn] : 0.f;
        if (has_bn) {
            g4[ni] = bn_g[gn]; b4[ni] = bn_b[gn]; mu4[ni] = bn_mu[gn];
            rs4[ni] = rsqrtf(bn_var[gn] + 1e-3f);
        }
    }
#pragma unroll
    for (int mi = 0; mi < 8; ++mi) {
        const int gm0 = m0 + wm * 128 + mi * 16 + quad * 4;
#pragma unroll
        for (int r = 0; r < 4; ++r) {
            const float bm_ = bias_m ? bias_m[gm0 + r] : 0.f;
            const size_t rowb = (size_t)(gm0 + r) * LDC + n0 + wn * 64 + r16;
#pragma unroll
            for (int ni = 0; ni < 4; ++ni) {
                float v = acc[mi][ni][r] + addn4[ni] + bm_;
                if (has_bn) {
                    v = g4[ni] * (v - mu4[ni]) * rs4[ni] + b4[ni];
                    v = fmaxf(v, 0.f);
                }
                if (Cfb) Cfb[rowb + ni * 16] = v;
                else     Cb[rowb + ni * 16]  = f2bf(v);
            }
        }
    }
}

#undef TILE_BODY
#undef MFMA_PH
#undef RD_B
#undef RD_A
#undef ST_B
#undef ST_A
#undef PRIO0
#undef PRIO1
#undef LGKM0
#undef BAR

// kp split-K reduce: kpb[b][j] = bf16( sum_p acc[b*8+p][j] )
__global__ __launch_bounds__(256) void reduce_kp(
    const float* __restrict__ acc, unsigned short* __restrict__ kpb)
{
    const int j = (blockIdx.x * 256 + threadIdx.x) * 4;
    const int b = j >> 17, jj = j & 131071;
    const float* base = acc + (size_t)b * 8 * 131072 + jj;
    float4 s = *(const float4*)base;
#pragma unroll
    for (int p = 1; p < 8; ++p) {
        const float4 v = *(const float4*)(base + (size_t)p * 131072);
        s.x += v.x; s.y += v.y; s.z += v.z; s.w += v.w;
    }
    kpb[j + 0] = f2bf(s.x); kpb[j + 1] = f2bf(s.y);
    kpb[j + 2] = f2bf(s.z); kpb[j + 3] = f2bf(s.w);
}

// ---------------------------------------------------------------------------
// MFMA flash-attention (unchanged; channel order o' = h*64+dh).
// ---------------------------------------------------------------------------
__global__ __launch_bounds__(256) void attn_fused(
    const unsigned short* __restrict__ qT,
    const unsigned short* __restrict__ kp,
    unsigned short* __restrict__ msgT)
{
    constexpr int QS = 72, KS = 72, VS = 136, PS = 136;
    __shared__ __align__(16) unsigned short QKP[128 * QS + 128 * KS];
    __shared__ __align__(16) unsigned short Vs[64 * VS];
    unsigned short* Qs = QKP;
    unsigned short* Ks = QKP + 128 * QS;
    unsigned short* Ps = QKP;

    const int t = threadIdx.x;
    const int lane = t & 63, w = t >> 6;
    const int r16 = lane & 15, quad = lane >> 4;
    const int h = blockIdx.y, n0 = blockIdx.x * 128;
    const size_t b = blockIdx.z;

    const unsigned short* qbase = qT + (b * 4096 + n0) * 1024 + h * 64;
    const unsigned short* kbase = kp + (b * 1024 + h * 64) * 128;

#pragma unroll
    for (int i = 0; i < 4; ++i) {
        const int c = i * 256 + t;
        const int n = c >> 3, dh0 = (c & 7) * 8;
        *(int4*)&Qs[n * QS + dh0] = *(const int4*)&qbase[(size_t)n * 1024 + dh0];
    }
#pragma unroll
    for (int i = 0; i < 4; ++i) {
        const int c = i * 256 + t;
        const int kkq = c & 3, dh = (c >> 2) & 63, kkh = c >> 8;
        const int kk0 = kkh * 32 + kkq * 8;
        const bf16x8 v = *(const bf16x8*)&kbase[(size_t)dh * 128 + kk0];
        *(bf16x8*)&Vs[dh * VS + kk0] = v;
        const unsigned short* vs = (const unsigned short*)&v;
#pragma unroll
        for (int j = 0; j < 8; ++j) Ks[(kk0 + j) * KS + dh] = vs[j];
    }
    __syncthreads();

    f32x4 S[2][8];
    const f32x4 zf = {0.f, 0.f, 0.f, 0.f};
#pragma unroll
    for (int mi = 0; mi < 2; ++mi)
#pragma unroll
        for (int ni = 0; ni < 8; ++ni) S[mi][ni] = zf;

    bf16x8 aq[2][2];
#pragma unroll
    for (int mi = 0; mi < 2; ++mi)
#pragma unroll
        for (int ks = 0; ks < 2; ++ks)
            aq[mi][ks] = *(const bf16x8*)&Qs[(w * 32 + mi * 16 + r16) * QS + ks * 32 + quad * 8];
#pragma unroll
    for (int ni = 0; ni < 8; ++ni) {
        const bf16x8 b0 = *(const bf16x8*)&Ks[(ni * 16 + r16) * KS + quad * 8];
        const bf16x8 b1 = *(const bf16x8*)&Ks[(ni * 16 + r16) * KS + 32 + quad * 8];
#pragma unroll
        for (int mi = 0; mi < 2; ++mi) {
            S[mi][ni] = __builtin_amdgcn_mfma_f32_16x16x32_bf16(aq[mi][0], b0, S[mi][ni], 0, 0, 0);
            S[mi][ni] = __builtin_amdgcn_mfma_f32_16x16x32_bf16(aq[mi][1], b1, S[mi][ni], 0, 0, 0);
        }
    }

    __syncthreads();

    float linv[2][4];
#pragma unroll
    for (int mi = 0; mi < 2; ++mi) {
        float e[8][4];
        float rs0 = 0.f, rs1 = 0.f, rs2 = 0.f, rs3 = 0.f;
#pragma unroll
        for (int ni = 0; ni < 8; ++ni) {
            e[ni][0] = __expf(S[mi][ni][0] * 0.125f); rs0 += e[ni][0];
            e[ni][1] = __expf(S[mi][ni][1] * 0.125f); rs1 += e[ni][1];
            e[ni][2] = __expf(S[mi][ni][2] * 0.125f); rs2 += e[ni][2];
            e[ni][3] = __expf(S[mi][ni][3] * 0.125f); rs3 += e[ni][3];
        }
        float rs[4] = {rs0, rs1, rs2, rs3};
#pragma unroll
        for (int r = 0; r < 4; ++r) {
            float s = rs[r];
            s += __shfl_xor(s, 1); s += __shfl_xor(s, 2);
            s += __shfl_xor(s, 4); s += __shfl_xor(s, 8);
            linv[mi][r] = 1.f / s;
        }
#pragma unroll
        for (int ni = 0; ni < 8; ++ni)
#pragma unroll
            for (int r = 0; r < 4; ++r)
                Ps[(w * 32 + mi * 16 + quad * 4 + r) * PS + ni * 16 + r16] = f2bf(e[ni][r]);
    }
    __syncthreads();

    f32x4 O[2][4];
#pragma unroll
    for (int mi = 0; mi < 2; ++mi)
#pragma unroll
        for (int ni = 0; ni < 4; ++ni) O[mi][ni] = zf;

    bf16x8 ap[2][4];
#pragma unroll
    for (int mi = 0; mi < 2; ++mi)
#pragma unroll
        for (int ks = 0; ks < 4; ++ks)
            ap[mi][ks] = *(const bf16x8*)&Ps[(w * 32 + mi * 16 + r16) * PS + ks * 32 + quad * 8];
#pragma unroll
    for (int ni = 0; ni < 4; ++ni)
#pragma unroll
        for (int ks = 0; ks < 4; ++ks) {
            const bf16x8 bv = *(const bf16x8*)&Vs[(ni * 16 + r16) * VS + ks * 32 + quad * 8];
#pragma unroll
            for (int mi = 0; mi < 2; ++mi)
                O[mi][ni] = __builtin_amdgcn_mfma_f32_16x16x32_bf16(ap[mi][ks], bv, O[mi][ni], 0, 0, 0);
        }

    unsigned short* ob = msgT + (b * 4096 + n0) * 1024 + h * 64;
#pragma unroll
    for (int mi = 0; mi < 2; ++mi)
#pragma unroll
        for (int ni = 0; ni < 4; ++ni)
#pragma unroll
            for (int r = 0; r < 4; ++r)
                ob[(size_t)(w * 32 + mi * 16 + quad * 4 + r) * 1024 + ni * 16 + r16] =
                    f2bf(O[mi][ni][r] * linv[mi][r]);
}

// ---------------------------------------------------------------------------
extern "C" void kernel_launch(void* const* d_in, const int* in_sizes, int n_in,
                              void* d_out, int out_size, void* d_ws, size_t ws_size,
                              hipStream_t stream)
{
    (void)in_sizes; (void)n_in; (void)out_size; (void)ws_size;
    const float* x    = (const float*)d_in[0];
    const float* srcp = (const float*)d_in[1];
    const float* Wq   = (const float*)d_in[2];
    const float* bq   = (const float*)d_in[3];
    const float* Wk   = (const float*)d_in[4];
    const float* bk   = (const float*)d_in[5];
    const float* proj = (const float*)d_in[6];
    const float* Wm   = (const float*)d_in[7];
    const float* bm   = (const float*)d_in[8];
    const float* W1   = (const float*)d_in[9];
    const float* b1   = (const float*)d_in[10];
    const float* gam  = (const float*)d_in[11];
    const float* bet  = (const float*)d_in[12];
    const float* mu   = (const float*)d_in[13];
    const float* var  = (const float*)d_in[14];
    const float* W2   = (const float*)d_in[15];
    const float* b2   = (const float*)d_in[16];
    float* out = (float*)d_out;
    unsigned short* ws = (unsigned short*)d_ws;

    const long long E = 16777216LL;  // 4*4096*1024
    unsigned short* xt  = ws;
    unsigned short* st  = xt + E;
    unsigned short* qt  = st + E;
    unsigned short* kc  = qt + E;
    unsigned short* ht  = kc + E;
    unsigned short* pT  = ht + 2 * E;
    unsigned short* kpb = pT + 524288;
    unsigned short* wqb = kpb + 524288;
    unsigned short* wkb = wqb + 1048576;
    unsigned short* wmb = wkb + 1048576;
    unsigned short* w1b = wmb + 1048576;
    unsigned short* w2b = w1b + 4194304;
    float* bqp = (float*)(w2b + 2097152);
    float* bkp = bqp + 1024;
    float* kpacc = (float*)ht;  // kp split-K partials alias ht (not yet live)

    cvt_transpose_xs<<<dim3(128, 32, 8), 256, 0, stream>>>(x, srcp, xt, st);
    cvt_transpose<<<dim3(4, 128, 1), 256, 0, stream>>>(proj, pT, 4096, 128);
    prep_weights<<<9220, 256, 0, stream>>>(Wq, Wk, Wm, W1, W2, bq, bk,
                                           wqb, wkb, wmb, w1b, w2b, bqp, bkp);

    // q = Wq @ x           (M=4096 seq, N'=1024 out-ch, K=1024)
    gemm256<1024, 1024, 1024, 1024, false><<<dim3(4, 16, 4), 512, 0, stream>>>(
        xt, nullptr, 1024, wqb, qt, nullptr,
        4096LL * 1024, 0LL, 4096LL * 1024, nullptr, bqp,
        nullptr, nullptr, nullptr, nullptr);
    // kc = Wk @ source     (M=1024 out-ch, N'=4096 seq, K=1024)
    gemm256<1024, 1024, 4096, 1024, false><<<dim3(16, 4, 4), 512, 0, stream>>>(
        wkb, nullptr, 1024, st, kc, nullptr,
        0LL, 4096LL * 1024, 1024LL * 4096, bkp, nullptr,
        nullptr, nullptr, nullptr, nullptr);
    // kp projection: N'=128 too narrow for the 256-tile — keep 128-tile split-K.
    gemm_bt<4096, 4096, 128, 4096, 8, false><<<dim3(1, 8, 32), 256, 0, stream>>>(
        kc, nullptr, 4096, pT, nullptr, kpacc,
        1024LL * 4096, 0LL, 1024LL * 128, nullptr, nullptr,
        nullptr, nullptr, nullptr, nullptr);
    reduce_kp<<<512, 256, 0, stream>>>(kpacc, kpb);
    attn_fused<<<dim3(32, 16, 4), 256, 0, stream>>>(qt, kpb, qt);
    // merge                (M=4096 seq, N'=1024, K=1024)
    gemm256<1024, 1024, 1024, 1024, false><<<dim3(4, 16, 4), 512, 0, stream>>>(
        qt, nullptr, 1024, wmb, st, nullptr,
        4096LL * 1024, 0LL, 4096LL * 1024, nullptr, bm,
        nullptr, nullptr, nullptr, nullptr);
    // mlp1 + BN + ReLU     (M=4096, N'=2048, K=2048 concat)
    gemm256<1024, 2048, 2048, 2048, true><<<dim3(8, 16, 4), 512, 0, stream>>>(
        xt, st, 1024, w1b, ht, nullptr,
        4096LL * 1024, 0LL, 4096LL * 2048, nullptr, b1,
        gam, bet, mu, var);
    // mlp2 -> f32 out      (M=1024 out-ch, N'=4096 seq, K=2048)
    gemm256<2048, 2048, 4096, 2048, false><<<dim3(16, 4, 4), 512, 0, stream>>>(
        w2b, nullptr, 2048, ht, nullptr, out,
        0LL, 4096LL * 2048, 1024LL * 4096, b2, nullptr,
        nullptr, nullptr, nullptr, nullptr);
}